// Round 6
// baseline (307.083 us; speedup 1.0000x reference)
//
#include <hip/hip_runtime.h>

#define H 16
#define NSEQ 2048
#define HD 64
#define CDIM 1024

typedef __attribute__((ext_vector_type(8))) short s8v;
typedef __attribute__((ext_vector_type(4))) float f4v;
typedef __attribute__((ext_vector_type(16))) float f16v;
typedef __attribute__((ext_vector_type(4))) unsigned u4v;

#define GLL(g, l) __builtin_amdgcn_global_load_lds( \
    (const __attribute__((address_space(1))) void*)(g), \
    (__attribute__((address_space(3))) void*)(l), 16, 0, 0)

__device__ __forceinline__ short f2bf(float f) {  // RNE-ish
  unsigned u = __float_as_uint(f);
  unsigned r = (u + 0x7fffu + ((u >> 16) & 1u)) >> 16;
  return (short)r;
}
__device__ __forceinline__ short f2bf_fast(float f) {
  return (short)((__float_as_uint(f) + 0x8000u) >> 16);
}
__device__ __forceinline__ unsigned pk(float a, float b) {  // (bf16(a) low, bf16(b) high)
  unsigned ua = __float_as_uint(a) + 0x8000u;
  unsigned ub = __float_as_uint(b) + 0x8000u;
  return __builtin_amdgcn_perm(ub, ua, 0x07060302);
}

// ---------------- fused fp32->bf16 (x, qkv_w, proj_w) + gate MLP ----------------
__global__ __launch_bounds__(256) void cvt_gate_kernel(
    const float* __restrict__ a, const float* __restrict__ b, const float* __restrict__ c,
    const float* __restrict__ mask,
    const float* __restrict__ g1w, const float* __restrict__ g1b,
    const float* __restrict__ g2w, const float* __restrict__ g2b,
    short* __restrict__ oa, short* __restrict__ ob, short* __restrict__ oc,
    float* __restrict__ gate) {
  int i = blockIdx.x * 256 + threadIdx.x;
  if (i >= 2097152) {  // last 16 blocks: gate MLP for 4096 (b,n)
    int j = i - 2097152;
    float m = mask[j];
    float acc = 0.f;
    for (int k = 0; k < 256; k++) {
      float h = fmaxf(m * g1w[k] + g1b[k], 0.f);
      acc += g2w[k] * h;
    }
    gate[j] = 1.f / (1.f + __expf(-(acc + g2b[0])));
    return;
  }
  const float* src; short* dst; int j;
  if (i < 1048576)      { src = a; dst = oa; j = i; }
  else if (i < 1835008) { src = b; dst = ob; j = i - 1048576; }
  else                  { src = c; dst = oc; j = i - 1835008; }
  float4 f = ((const float4*)src)[j];
  short4 s;
  s.x = f2bf(f.x); s.y = f2bf(f.y); s.z = f2bf(f.z); s.w = f2bf(f.w);
  ((short4*)dst)[j] = s;
}

// ---------------- QKV GEMM, swapped orientation: A=W (feat), B=X (token) ----------------
__global__ __launch_bounds__(256) void gemm_qkv(const short* __restrict__ X,
    const short* __restrict__ W, const float* __restrict__ bias, const float* __restrict__ gate,
    short* __restrict__ qws, short* __restrict__ kws, short* __restrict__ vtws) {
  __shared__ __align__(16) short Ft[8192];   // W tile, 2 bufs of 128x32
  __shared__ __align__(16) short Tt[8192];   // X tile, 2 bufs
  const int K = CDIM;
  int tid = threadIdx.x;
  int lane = tid & 63, w = tid >> 6;
  int quad = lane >> 4, l15 = lane & 15;
  int wm = w >> 1, wn = w & 1;
  long featBase = (long)blockIdx.x * 128;
  long tokBase  = (long)blockIdx.y * 128;
  const f4v fz = {0.f, 0.f, 0.f, 0.f};
  f4v acc[4][4];
#pragma unroll
  for (int i = 0; i < 4; i++)
#pragma unroll
    for (int j = 0; j < 4; j++) acc[i][j] = fz;

  int j0 = tid, j1 = 256 + tid;
  int sr0 = j0 >> 2, sp0 = j0 & 3, sc0 = sp0 ^ ((sr0 >> 1) & 3);
  int sr1 = j1 >> 2, sp1 = j1 & 3, sc1 = sp1 ^ ((sr1 >> 1) & 3);
  const short* Wa = W + (featBase + sr0) * K + sc0 * 8;
  const short* Wb = W + (featBase + sr1) * K + sc1 * 8;
  const short* Xa = X + (tokBase + sr0) * K + sc0 * 8;
  const short* Xb = X + (tokBase + sr1) * K + sc1 * 8;

  GLL(Wa, &Ft[j0 * 8]);
  GLL(Wb, &Ft[j1 * 8]);
  GLL(Xa, &Tt[j0 * 8]);
  GLL(Xb, &Tt[j1 * 8]);

  for (int it = 0; it < 32; it++) {
    int cur = (it & 1) * 4096;
    __syncthreads();
    s8v a[4], b[4];
#pragma unroll
    for (int mi = 0; mi < 4; mi++) {
      int row = wm * 64 + mi * 16 + l15;
      a[mi] = *(const s8v*)&Ft[cur + row * 32 + ((quad ^ ((row >> 1) & 3)) * 8)];
    }
#pragma unroll
    for (int ni = 0; ni < 4; ni++) {
      int row = wn * 64 + ni * 16 + l15;
      b[ni] = *(const s8v*)&Tt[cur + row * 32 + ((quad ^ ((row >> 1) & 3)) * 8)];
    }
    if (it < 31) {
      int nb = 4096 - cur;
      int k0 = (it + 1) * 32;
      GLL(Wa + k0, &Ft[nb + j0 * 8]);
      GLL(Wb + k0, &Ft[nb + j1 * 8]);
      GLL(Xa + k0, &Tt[nb + j0 * 8]);
      GLL(Xb + k0, &Tt[nb + j1 * 8]);
    }
#pragma unroll
    for (int mi = 0; mi < 4; mi++)
#pragma unroll
      for (int ni = 0; ni < 4; ni++)
        acc[mi][ni] = __builtin_amdgcn_mfma_f32_16x16x32_bf16(a[mi], b[ni], acc[mi][ni], 0, 0, 0);
  }
#pragma unroll
  for (int mi = 0; mi < 4; mi++) {
    int feat0 = (int)featBase + wm * 64 + mi * 16 + quad * 4;
    int which = feat0 >> 10, cc = feat0 & 1023;
    int hh = cc >> 6, dd = cc & 63;
    f4v b4 = *(const f4v*)&bias[feat0];
#pragma unroll
    for (int ni = 0; ni < 4; ni++) {
      int token = (int)tokBase + wn * 64 + ni * 16 + l15;
      int bb = token >> 11, nn = token & 2047;
      if (which == 0) {
        short4 pv;
        pv.x = f2bf((acc[mi][ni][0] + b4[0]) * 0.125f);
        pv.y = f2bf((acc[mi][ni][1] + b4[1]) * 0.125f);
        pv.z = f2bf((acc[mi][ni][2] + b4[2]) * 0.125f);
        pv.w = f2bf((acc[mi][ni][3] + b4[3]) * 0.125f);
        *(short4*)&qws[((bb * H + hh) * NSEQ + nn) * HD + dd] = pv;
      } else if (which == 1) {
        float gl = gate[token] * 1.44269504f;
        short4 pv;
        pv.x = f2bf((acc[mi][ni][0] + b4[0]) * gl);
        pv.y = f2bf((acc[mi][ni][1] + b4[1]) * gl);
        pv.z = f2bf((acc[mi][ni][2] + b4[2]) * gl);
        pv.w = f2bf((acc[mi][ni][3] + b4[3]) * gl);
        *(short4*)&kws[((bb * H + hh) * NSEQ + nn) * HD + dd] = pv;
      } else {
#pragma unroll
        for (int r = 0; r < 4; r++)
          vtws[((bb * H + hh) * HD + dd + r) * NSEQ + nn] = f2bf(acc[mi][ni][r] + b4[r]);
      }
    }
  }
}

// ---------------- Proj GEMM: 64x128 tile, dbuf single-barrier ----------------
__global__ __launch_bounds__(256) void gemm_proj(const short* __restrict__ X,
    const short* __restrict__ W, const float* __restrict__ bias, float* __restrict__ out) {
  __shared__ __align__(16) short At[4096];
  __shared__ __align__(16) short Bt[8192];
  const int K = CDIM;
  int tid = threadIdx.x;
  int lane = tid & 63, w = tid >> 6;
  int quad = lane >> 4, l15 = lane & 15;
  int wm = w >> 1, wn = w & 1;
  long rowBase = (long)blockIdx.y * 64;
  long colBase = (long)blockIdx.x * 128;
  const f4v fz = {0.f, 0.f, 0.f, 0.f};
  f4v acc[2][4];
#pragma unroll
  for (int i = 0; i < 2; i++)
#pragma unroll
    for (int j = 0; j < 4; j++) acc[i][j] = fz;

  int j0 = tid, j1 = 256 + tid;
  int sr0 = j0 >> 2, sp0 = j0 & 3, sc0 = sp0 ^ ((sr0 >> 1) & 3);
  int sr1 = j1 >> 2, sp1 = j1 & 3, sc1 = sp1 ^ ((sr1 >> 1) & 3);
  const short* Xa = X + (rowBase + sr0) * K + sc0 * 8;
  const short* Wa = W + (colBase + sr0) * K + sc0 * 8;
  const short* Wb = W + (colBase + sr1) * K + sc1 * 8;

  GLL(Xa, &At[j0 * 8]);
  GLL(Wa, &Bt[j0 * 8]);
  GLL(Wb, &Bt[j1 * 8]);

  for (int it = 0; it < 32; it++) {
    int curA = (it & 1) * 2048, curB = (it & 1) * 4096;
    __syncthreads();
    s8v a[2], b[4];
#pragma unroll
    for (int mi = 0; mi < 2; mi++) {
      int row = wm * 32 + mi * 16 + l15;
      a[mi] = *(const s8v*)&At[curA + row * 32 + ((quad ^ ((row >> 1) & 3)) * 8)];
    }
#pragma unroll
    for (int ni = 0; ni < 4; ni++) {
      int row = wn * 64 + ni * 16 + l15;
      b[ni] = *(const s8v*)&Bt[curB + row * 32 + ((quad ^ ((row >> 1) & 3)) * 8)];
    }
    if (it < 31) {
      int nbA = 2048 - curA, nbB = 4096 - curB;
      int k0 = (it + 1) * 32;
      GLL(Xa + k0, &At[nbA + j0 * 8]);
      GLL(Wa + k0, &Bt[nbB + j0 * 8]);
      GLL(Wb + k0, &Bt[nbB + j1 * 8]);
    }
#pragma unroll
    for (int mi = 0; mi < 2; mi++)
#pragma unroll
      for (int ni = 0; ni < 4; ni++)
        acc[mi][ni] = __builtin_amdgcn_mfma_f32_16x16x32_bf16(a[mi], b[ni], acc[mi][ni], 0, 0, 0);
  }
#pragma unroll
  for (int mi = 0; mi < 2; mi++) {
    int row = (int)rowBase + wm * 32 + mi * 16 + quad * 4;
#pragma unroll
    for (int ni = 0; ni < 4; ni++) {
      int col = (int)colBase + wn * 64 + ni * 16 + l15;
      float bcol = bias[col];
#pragma unroll
      for (int r = 0; r < 4; r++)
        out[(long)(row + r) * CDIM + col] = acc[mi][ni][r] + bcol;
    }
  }
}

// ---------------- Flash attention v6: v5 structure, all-register inner loop ----------------
// 128-thread blocks (2 waves = key-halves wk). 64 qrows/block, BK=64, dbuf GLL pipeline,
// O^T orientation (A=V^T, B=P^T via hf key-quad shfl exchange). grid 1024 = (qt 32)x(bh 32).
__global__ __launch_bounds__(128, 2) void attn_kernel(const short* __restrict__ qws,
    const short* __restrict__ kws, const short* __restrict__ vtws,
    short* __restrict__ attn_out) {
  __shared__ __align__(16) char smem[32768];
  short* KB = (short*)smem;           // [2][64][64]
  short* VB = (short*)smem + 8192;    // [2][64][64]

  int tid = threadIdx.x;
  int lane = tid & 63;
  int wk = tid >> 6;                  // wave = key half
  int l31 = lane & 31, hf = lane >> 5;
  int bh = blockIdx.x & 31, qt = blockIdx.x >> 5;
  int b = bh >> 4, head = bh & 15;
  int qbase = qt * 64;

  // Q B-frags: qf[rt][ds] = B[n=qrow rt*32+l31][k=d ds*16+hf*8+j]
  s8v qf[2][4];
  {
    const short* qp = qws + ((long)bh * NSEQ + qbase + l31) * HD + hf * 8;
#pragma unroll
    for (int rt = 0; rt < 2; rt++)
#pragma unroll
      for (int ds = 0; ds < 4; ds++)
        qf[rt][ds] = *(const s8v*)&qp[rt * 32 * HD + ds * 16];
  }

  const f16v fz16 = {0.f,0.f,0.f,0.f,0.f,0.f,0.f,0.f,0.f,0.f,0.f,0.f,0.f,0.f,0.f,0.f};
  f16v oacc[2][2];   // [rt][nt] O^T: reg r -> d = nt*32+(r&3)+8*(r>>2)+4hf ; lane -> qrow rt*32+l31
#pragma unroll
  for (int rt = 0; rt < 2; rt++)
#pragma unroll
    for (int nt = 0; nt < 2; nt++) oacc[rt][nt] = fz16;
  float l_r0 = 0.f, l_r1 = 0.f;

  // staging: wave wk stages rows wk*32 + g*8 + r8 of K and V tiles, chunk c8^r8
  int r8 = lane >> 3, c8 = lane & 7;
  int row0 = wk * 32 + r8, row1 = row0 + 8, row2 = row0 + 16, row3 = row0 + 24;
  int sc = (c8 ^ r8) * 8;
  const short* kg0 = kws + ((long)bh * NSEQ + row0) * HD + sc;
  const short* kg1 = kws + ((long)bh * NSEQ + row1) * HD + sc;
  const short* kg2 = kws + ((long)bh * NSEQ + row2) * HD + sc;
  const short* kg3 = kws + ((long)bh * NSEQ + row3) * HD + sc;
  const short* vg0 = vtws + ((long)bh * HD + row0) * NSEQ + sc;
  const short* vg1 = vtws + ((long)bh * HD + row1) * NSEQ + sc;
  const short* vg2 = vtws + ((long)bh * HD + row2) * NSEQ + sc;
  const short* vg3 = vtws + ((long)bh * HD + row3) * NSEQ + sc;
  int lds0 = (wk * 32) * 64 + lane * 8;

  // prologue: tile 0 -> buf 0
  GLL(kg0, KB + lds0);
  GLL(kg1, KB + lds0 + 512);
  GLL(kg2, KB + lds0 + 1024);
  GLL(kg3, KB + lds0 + 1536);
  GLL(vg0, VB + lds0);
  GLL(vg1, VB + lds0 + 512);
  GLL(vg2, VB + lds0 + 1024);
  GLL(vg3, VB + lds0 + 1536);

  for (int it = 0; it < 32; it++) {
    int cur = (it & 1) * 4096;
    __syncthreads();
    const short* Kc = KB + cur;
    const short* Vc = VB + cur;
    s8v ak[4];
#pragma unroll
    for (int ds = 0; ds < 4; ds++)
      ak[ds] = *(const s8v*)&Kc[(wk * 32 + l31) * 64 + (((2 * ds + hf) ^ (l31 & 7)) * 8)];
    s8v av[2][2];
#pragma unroll
    for (int nt = 0; nt < 2; nt++)
#pragma unroll
      for (int ks = 0; ks < 2; ks++)
        av[nt][ks] = *(const s8v*)&Vc[(nt * 32 + l31) * 64 + (((wk * 4 + ks * 2 + hf) ^ (l31 & 7)) * 8)];
    if (it < 31) {
      int nb = 4096 - cur;
      long koff = (long)(it + 1) * 64 * HD;
      int voff = (it + 1) * 64;
      GLL(kg0 + koff, KB + nb + lds0);
      GLL(kg1 + koff, KB + nb + lds0 + 512);
      GLL(kg2 + koff, KB + nb + lds0 + 1024);
      GLL(kg3 + koff, KB + nb + lds0 + 1536);
      GLL(vg0 + voff, VB + nb + lds0);
      GLL(vg1 + voff, VB + nb + lds0 + 512);
      GLL(vg2 + voff, VB + nb + lds0 + 1024);
      GLL(vg3 + voff, VB + nb + lds0 + 1536);
    }
    // per q-row-tile: S^T -> exp2 -> pack -> exchange -> PV (all registers)
#pragma unroll
    for (int rt = 0; rt < 2; rt++) {
      f16v s = fz16;
#pragma unroll
      for (int ds = 0; ds < 4; ds++)
        s = __builtin_amdgcn_mfma_f32_32x32x16_bf16(ak[ds], qf[rt][ds], s, 0, 0, 0);
      f16v pv;
#pragma unroll
      for (int i = 0; i < 16; i++) pv[i] = __builtin_amdgcn_exp2f(s[i]);
      float ls = 0.f;
#pragma unroll
      for (int i = 0; i < 16; i++) ls += pv[i];
      ls += __shfl_xor(ls, 32);
      if (rt == 0) l_r0 += ls; else l_r1 += ls;
      // pack: dg{2g},dg{2g+1} hold keys 8g+4hf+{0..3} for qrow l31
      unsigned d0 = pk(pv[0],  pv[1]),  d1 = pk(pv[2],  pv[3]);
      unsigned d2 = pk(pv[4],  pv[5]),  d3 = pk(pv[6],  pv[7]);
      unsigned d4 = pk(pv[8],  pv[9]),  d5 = pk(pv[10], pv[11]);
      unsigned d6 = pk(pv[12], pv[13]), d7 = pk(pv[14], pv[15]);
      // ks = 0 (quads g=0,1)
      {
        unsigned send0 = hf ? d0 : d2, send1 = hf ? d1 : d3;
        unsigned own0  = hf ? d2 : d0, own1  = hf ? d3 : d1;
        unsigned recv0 = (unsigned)__shfl_xor((int)send0, 32);
        unsigned recv1 = (unsigned)__shfl_xor((int)send1, 32);
        u4v t;
        t.x = hf ? recv0 : own0;
        t.y = hf ? recv1 : own1;
        t.z = hf ? own0 : recv0;
        t.w = hf ? own1 : recv1;
        s8v bv = __builtin_bit_cast(s8v, t);
#pragma unroll
        for (int nt = 0; nt < 2; nt++)
          oacc[rt][nt] = __builtin_amdgcn_mfma_f32_32x32x16_bf16(av[nt][0], bv, oacc[rt][nt], 0, 0, 0);
      }
      // ks = 1 (quads g=2,3)
      {
        unsigned send0 = hf ? d4 : d6, send1 = hf ? d5 : d7;
        unsigned own0  = hf ? d6 : d4, own1  = hf ? d7 : d5;
        unsigned recv0 = (unsigned)__shfl_xor((int)send0, 32);
        unsigned recv1 = (unsigned)__shfl_xor((int)send1, 32);
        u4v t;
        t.x = hf ? recv0 : own0;
        t.y = hf ? recv1 : own1;
        t.z = hf ? own0 : recv0;
        t.w = hf ? own1 : recv1;
        s8v bv = __builtin_bit_cast(s8v, t);
#pragma unroll
        for (int nt = 0; nt < 2; nt++)
          oacc[rt][nt] = __builtin_amdgcn_mfma_f32_32x32x16_bf16(av[nt][1], bv, oacc[rt][nt], 0, 0, 0);
      }
    }
  }

  // ---- combine key halves ----
  __syncthreads();
  float* od = (float*)smem;            // region rt at rt*2176 floats: [32 qrow][68 pitch]
  float* ld = (float*)(smem + 17408);  // [2][32]
  {
    int rt = 1 - wk;  // dump the half the partner will store
#pragma unroll
    for (int nt = 0; nt < 2; nt++)
#pragma unroll
      for (int g = 0; g < 4; g++) {
        f4v t = {oacc[rt][nt][4 * g], oacc[rt][nt][4 * g + 1],
                 oacc[rt][nt][4 * g + 2], oacc[rt][nt][4 * g + 3]};
        *(f4v*)&od[rt * 2176 + l31 * 68 + nt * 32 + 8 * g + 4 * hf] = t;
      }
    ld[rt * 32 + l31] = wk ? l_r0 : l_r1;
  }
  __syncthreads();
  {
    int rt = wk;      // store own half combined with partner's dump
    float lt = (wk ? l_r1 : l_r0) + ld[rt * 32 + l31];
    float li = __builtin_amdgcn_rcpf(lt);
    long outbase = ((long)b * NSEQ + qbase + rt * 32 + l31) * CDIM + head * HD;
#pragma unroll
    for (int nt = 0; nt < 2; nt++)
#pragma unroll
      for (int g = 0; g < 4; g++) {
        f4v part = *(const f4v*)&od[rt * 2176 + l31 * 68 + nt * 32 + 8 * g + 4 * hf];
        short4 pvv;
        pvv.x = f2bf_fast((oacc[rt][nt][4 * g]     + part[0]) * li);
        pvv.y = f2bf_fast((oacc[rt][nt][4 * g + 1] + part[1]) * li);
        pvv.z = f2bf_fast((oacc[rt][nt][4 * g + 2] + part[2]) * li);
        pvv.w = f2bf_fast((oacc[rt][nt][4 * g + 3] + part[3]) * li);
        *(short4*)&attn_out[outbase + nt * 32 + 8 * g + 4 * hf] = pvv;
      }
  }
}

extern "C" void kernel_launch(void* const* d_in, const int* in_sizes, int n_in,
                              void* d_out, int out_size, void* d_ws, size_t ws_size,
                              hipStream_t stream) {
  const float* x     = (const float*)d_in[0];
  const float* mask  = (const float*)d_in[1];
  const float* qkvw  = (const float*)d_in[2];
  const float* qkvb  = (const float*)d_in[3];
  const float* projw = (const float*)d_in[4];
  const float* projb = (const float*)d_in[5];
  const float* g1w   = (const float*)d_in[6];
  const float* g1b   = (const float*)d_in[7];
  const float* g2w   = (const float*)d_in[8];
  const float* g2b   = (const float*)d_in[9];
  float* out = (float*)d_out;

  char* ws = (char*)d_ws;
  short* x_bf    = (short*)(ws);               // 8 MiB
  short* w_qkv   = (short*)(ws + 8388608);     // 6 MiB
  short* w_proj  = (short*)(ws + 14680064);    // 2 MiB
  short* q_ws    = (short*)(ws + 16777216);    // 8 MiB (pre-scaled by 1/8)
  short* k_ws    = (short*)(ws + 25165824);    // 8 MiB (pre-scaled by gate*log2e)
  short* vt_ws   = (short*)(ws + 33554432);    // 8 MiB (transposed: b,h,d,n)
  short* attn_bf = (short*)(ws + 41943040);    // 8 MiB
  float* gate    = (float*)(ws + 50331648);    // 16 KiB

  cvt_gate_kernel<<<8208, 256, 0, stream>>>(x, qkvw, projw, mask, g1w, g1b, g2w, g2b,
                                            x_bf, w_qkv, w_proj, gate);

  dim3 gq(24, 32);
  gemm_qkv<<<gq, 256, 0, stream>>>(x_bf, w_qkv, qkvb, gate, q_ws, k_ws, vt_ws);

  attn_kernel<<<1024, 128, 0, stream>>>(q_ws, k_ws, vt_ws, attn_bf);

  dim3 gp(8, 64);
  gemm_proj<<<gp, 256, 0, stream>>>(attn_bf, w_proj, projb, out);
}

// Round 7
// 205.845 us; speedup vs baseline: 1.4918x; 1.4918x over previous
//
#include <hip/hip_runtime.h>

#define H 16
#define NSEQ 2048
#define HD 64
#define CDIM 1024

typedef __attribute__((ext_vector_type(8))) short s8v;
typedef __attribute__((ext_vector_type(4))) float f4v;
typedef __attribute__((ext_vector_type(16))) float f16v;
typedef __attribute__((ext_vector_type(4))) unsigned u4v;

#define GLL(g, l) __builtin_amdgcn_global_load_lds( \
    (const __attribute__((address_space(1))) void*)(g), \
    (__attribute__((address_space(3))) void*)(l), 16, 0, 0)

__device__ __forceinline__ short f2bf(float f) {  // RNE-ish
  unsigned u = __float_as_uint(f);
  unsigned r = (u + 0x7fffu + ((u >> 16) & 1u)) >> 16;
  return (short)r;
}
__device__ __forceinline__ short f2bf_fast(float f) {
  return (short)((__float_as_uint(f) + 0x8000u) >> 16);
}
__device__ __forceinline__ unsigned pk(float a, float b) {  // (bf16(a) low, bf16(b) high)
  unsigned ua = __float_as_uint(a) + 0x8000u;
  unsigned ub = __float_as_uint(b) + 0x8000u;
  return __builtin_amdgcn_perm(ub, ua, 0x07060302);
}

// ---------------- fused fp32->bf16 (x, qkv_w, proj_w) + gate MLP ----------------
__global__ __launch_bounds__(256) void cvt_gate_kernel(
    const float* __restrict__ a, const float* __restrict__ b, const float* __restrict__ c,
    const float* __restrict__ mask,
    const float* __restrict__ g1w, const float* __restrict__ g1b,
    const float* __restrict__ g2w, const float* __restrict__ g2b,
    short* __restrict__ oa, short* __restrict__ ob, short* __restrict__ oc,
    float* __restrict__ gate) {
  int i = blockIdx.x * 256 + threadIdx.x;
  if (i >= 2097152) {  // last 16 blocks: gate MLP for 4096 (b,n)
    int j = i - 2097152;
    float m = mask[j];
    float acc = 0.f;
    for (int k = 0; k < 256; k++) {
      float h = fmaxf(m * g1w[k] + g1b[k], 0.f);
      acc += g2w[k] * h;
    }
    gate[j] = 1.f / (1.f + __expf(-(acc + g2b[0])));
    return;
  }
  const float* src; short* dst; int j;
  if (i < 1048576)      { src = a; dst = oa; j = i; }
  else if (i < 1835008) { src = b; dst = ob; j = i - 1048576; }
  else                  { src = c; dst = oc; j = i - 1835008; }
  float4 f = ((const float4*)src)[j];
  short4 s;
  s.x = f2bf(f.x); s.y = f2bf(f.y); s.z = f2bf(f.z); s.w = f2bf(f.w);
  ((short4*)dst)[j] = s;
}

// ---------------- QKV GEMM, swapped orientation: A=W (feat), B=X (token) ----------------
__global__ __launch_bounds__(256) void gemm_qkv(const short* __restrict__ X,
    const short* __restrict__ W, const float* __restrict__ bias, const float* __restrict__ gate,
    short* __restrict__ qws, short* __restrict__ kws, short* __restrict__ vtws) {
  __shared__ __align__(16) short Ft[8192];   // W tile, 2 bufs of 128x32
  __shared__ __align__(16) short Tt[8192];   // X tile, 2 bufs
  const int K = CDIM;
  int tid = threadIdx.x;
  int lane = tid & 63, w = tid >> 6;
  int quad = lane >> 4, l15 = lane & 15;
  int wm = w >> 1, wn = w & 1;
  long featBase = (long)blockIdx.x * 128;
  long tokBase  = (long)blockIdx.y * 128;
  const f4v fz = {0.f, 0.f, 0.f, 0.f};
  f4v acc[4][4];
#pragma unroll
  for (int i = 0; i < 4; i++)
#pragma unroll
    for (int j = 0; j < 4; j++) acc[i][j] = fz;

  int j0 = tid, j1 = 256 + tid;
  int sr0 = j0 >> 2, sp0 = j0 & 3, sc0 = sp0 ^ ((sr0 >> 1) & 3);
  int sr1 = j1 >> 2, sp1 = j1 & 3, sc1 = sp1 ^ ((sr1 >> 1) & 3);
  const short* Wa = W + (featBase + sr0) * K + sc0 * 8;
  const short* Wb = W + (featBase + sr1) * K + sc1 * 8;
  const short* Xa = X + (tokBase + sr0) * K + sc0 * 8;
  const short* Xb = X + (tokBase + sr1) * K + sc1 * 8;

  GLL(Wa, &Ft[j0 * 8]);
  GLL(Wb, &Ft[j1 * 8]);
  GLL(Xa, &Tt[j0 * 8]);
  GLL(Xb, &Tt[j1 * 8]);

  for (int it = 0; it < 32; it++) {
    int cur = (it & 1) * 4096;
    __syncthreads();
    s8v a[4], b[4];
#pragma unroll
    for (int mi = 0; mi < 4; mi++) {
      int row = wm * 64 + mi * 16 + l15;
      a[mi] = *(const s8v*)&Ft[cur + row * 32 + ((quad ^ ((row >> 1) & 3)) * 8)];
    }
#pragma unroll
    for (int ni = 0; ni < 4; ni++) {
      int row = wn * 64 + ni * 16 + l15;
      b[ni] = *(const s8v*)&Tt[cur + row * 32 + ((quad ^ ((row >> 1) & 3)) * 8)];
    }
    if (it < 31) {
      int nb = 4096 - cur;
      int k0 = (it + 1) * 32;
      GLL(Wa + k0, &Ft[nb + j0 * 8]);
      GLL(Wb + k0, &Ft[nb + j1 * 8]);
      GLL(Xa + k0, &Tt[nb + j0 * 8]);
      GLL(Xb + k0, &Tt[nb + j1 * 8]);
    }
#pragma unroll
    for (int mi = 0; mi < 4; mi++)
#pragma unroll
      for (int ni = 0; ni < 4; ni++)
        acc[mi][ni] = __builtin_amdgcn_mfma_f32_16x16x32_bf16(a[mi], b[ni], acc[mi][ni], 0, 0, 0);
  }
#pragma unroll
  for (int mi = 0; mi < 4; mi++) {
    int feat0 = (int)featBase + wm * 64 + mi * 16 + quad * 4;
    int which = feat0 >> 10, cc = feat0 & 1023;
    int hh = cc >> 6, dd = cc & 63;
    f4v b4 = *(const f4v*)&bias[feat0];
#pragma unroll
    for (int ni = 0; ni < 4; ni++) {
      int token = (int)tokBase + wn * 64 + ni * 16 + l15;
      int bb = token >> 11, nn = token & 2047;
      if (which == 0) {
        short4 pv;
        pv.x = f2bf((acc[mi][ni][0] + b4[0]) * 0.125f);
        pv.y = f2bf((acc[mi][ni][1] + b4[1]) * 0.125f);
        pv.z = f2bf((acc[mi][ni][2] + b4[2]) * 0.125f);
        pv.w = f2bf((acc[mi][ni][3] + b4[3]) * 0.125f);
        *(short4*)&qws[((bb * H + hh) * NSEQ + nn) * HD + dd] = pv;
      } else if (which == 1) {
        float gl = gate[token] * 1.44269504f;
        short4 pv;
        pv.x = f2bf((acc[mi][ni][0] + b4[0]) * gl);
        pv.y = f2bf((acc[mi][ni][1] + b4[1]) * gl);
        pv.z = f2bf((acc[mi][ni][2] + b4[2]) * gl);
        pv.w = f2bf((acc[mi][ni][3] + b4[3]) * gl);
        *(short4*)&kws[((bb * H + hh) * NSEQ + nn) * HD + dd] = pv;
      } else {
#pragma unroll
        for (int r = 0; r < 4; r++)
          vtws[((bb * H + hh) * HD + dd + r) * NSEQ + nn] = f2bf(acc[mi][ni][r] + b4[r]);
      }
    }
  }
}

// ---------------- Proj GEMM: 64x128 tile, dbuf single-barrier ----------------
__global__ __launch_bounds__(256) void gemm_proj(const short* __restrict__ X,
    const short* __restrict__ W, const float* __restrict__ bias, float* __restrict__ out) {
  __shared__ __align__(16) short At[4096];
  __shared__ __align__(16) short Bt[8192];
  const int K = CDIM;
  int tid = threadIdx.x;
  int lane = tid & 63, w = tid >> 6;
  int quad = lane >> 4, l15 = lane & 15;
  int wm = w >> 1, wn = w & 1;
  long rowBase = (long)blockIdx.y * 64;
  long colBase = (long)blockIdx.x * 128;
  const f4v fz = {0.f, 0.f, 0.f, 0.f};
  f4v acc[2][4];
#pragma unroll
  for (int i = 0; i < 2; i++)
#pragma unroll
    for (int j = 0; j < 4; j++) acc[i][j] = fz;

  int j0 = tid, j1 = 256 + tid;
  int sr0 = j0 >> 2, sp0 = j0 & 3, sc0 = sp0 ^ ((sr0 >> 1) & 3);
  int sr1 = j1 >> 2, sp1 = j1 & 3, sc1 = sp1 ^ ((sr1 >> 1) & 3);
  const short* Xa = X + (rowBase + sr0) * K + sc0 * 8;
  const short* Wa = W + (colBase + sr0) * K + sc0 * 8;
  const short* Wb = W + (colBase + sr1) * K + sc1 * 8;

  GLL(Xa, &At[j0 * 8]);
  GLL(Wa, &Bt[j0 * 8]);
  GLL(Wb, &Bt[j1 * 8]);

  for (int it = 0; it < 32; it++) {
    int curA = (it & 1) * 2048, curB = (it & 1) * 4096;
    __syncthreads();
    s8v a[2], b[4];
#pragma unroll
    for (int mi = 0; mi < 2; mi++) {
      int row = wm * 32 + mi * 16 + l15;
      a[mi] = *(const s8v*)&At[curA + row * 32 + ((quad ^ ((row >> 1) & 3)) * 8)];
    }
#pragma unroll
    for (int ni = 0; ni < 4; ni++) {
      int row = wn * 64 + ni * 16 + l15;
      b[ni] = *(const s8v*)&Bt[curB + row * 32 + ((quad ^ ((row >> 1) & 3)) * 8)];
    }
    if (it < 31) {
      int nbA = 2048 - curA, nbB = 4096 - curB;
      int k0 = (it + 1) * 32;
      GLL(Xa + k0, &At[nbA + j0 * 8]);
      GLL(Wa + k0, &Bt[nbB + j0 * 8]);
      GLL(Wb + k0, &Bt[nbB + j1 * 8]);
    }
#pragma unroll
    for (int mi = 0; mi < 2; mi++)
#pragma unroll
      for (int ni = 0; ni < 4; ni++)
        acc[mi][ni] = __builtin_amdgcn_mfma_f32_16x16x32_bf16(a[mi], b[ni], acc[mi][ni], 0, 0, 0);
  }
#pragma unroll
  for (int mi = 0; mi < 2; mi++) {
    int row = (int)rowBase + wm * 32 + mi * 16 + quad * 4;
#pragma unroll
    for (int ni = 0; ni < 4; ni++) {
      int col = (int)colBase + wn * 64 + ni * 16 + l15;
      float bcol = bias[col];
#pragma unroll
      for (int r = 0; r < 4; r++)
        out[(long)(row + r) * CDIM + col] = acc[mi][ni][r] + bcol;
    }
  }
}

// ---------------- Flash attention v7: v6 structure, epilogue with CONSTANT oacc indices ----------------
// (runtime-indexed oacc[rt] in v5/v6 demoted the MFMA accumulators to scratch: ~1 GB HBM writes)
__global__ __launch_bounds__(128, 2) void attn_kernel(const short* __restrict__ qws,
    const short* __restrict__ kws, const short* __restrict__ vtws,
    short* __restrict__ attn_out) {
  __shared__ __align__(16) char smem[32768];
  short* KB = (short*)smem;           // [2][64][64]
  short* VB = (short*)smem + 8192;    // [2][64][64]

  int tid = threadIdx.x;
  int lane = tid & 63;
  int wk = tid >> 6;                  // wave = key half
  int l31 = lane & 31, hf = lane >> 5;
  int bh = blockIdx.x & 31, qt = blockIdx.x >> 5;
  int b = bh >> 4, head = bh & 15;
  int qbase = qt * 64;

  // Q B-frags: qf[rt][ds] = B[n=qrow rt*32+l31][k=d ds*16+hf*8+j]
  s8v qf[2][4];
  {
    const short* qp = qws + ((long)bh * NSEQ + qbase + l31) * HD + hf * 8;
#pragma unroll
    for (int rt = 0; rt < 2; rt++)
#pragma unroll
      for (int ds = 0; ds < 4; ds++)
        qf[rt][ds] = *(const s8v*)&qp[rt * 32 * HD + ds * 16];
  }

  const f16v fz16 = {0.f,0.f,0.f,0.f,0.f,0.f,0.f,0.f,0.f,0.f,0.f,0.f,0.f,0.f,0.f,0.f};
  f16v oacc[2][2];   // [rt][nt] O^T: reg r -> d = nt*32+(r&3)+8*(r>>2)+4hf ; lane -> qrow rt*32+l31
#pragma unroll
  for (int rt = 0; rt < 2; rt++)
#pragma unroll
    for (int nt = 0; nt < 2; nt++) oacc[rt][nt] = fz16;
  float l_r0 = 0.f, l_r1 = 0.f;

  // staging: wave wk stages rows wk*32 + g*8 + r8 of K and V tiles, chunk c8^r8
  int r8 = lane >> 3, c8 = lane & 7;
  int row0 = wk * 32 + r8, row1 = row0 + 8, row2 = row0 + 16, row3 = row0 + 24;
  int sc = (c8 ^ r8) * 8;
  const short* kg0 = kws + ((long)bh * NSEQ + row0) * HD + sc;
  const short* kg1 = kws + ((long)bh * NSEQ + row1) * HD + sc;
  const short* kg2 = kws + ((long)bh * NSEQ + row2) * HD + sc;
  const short* kg3 = kws + ((long)bh * NSEQ + row3) * HD + sc;
  const short* vg0 = vtws + ((long)bh * HD + row0) * NSEQ + sc;
  const short* vg1 = vtws + ((long)bh * HD + row1) * NSEQ + sc;
  const short* vg2 = vtws + ((long)bh * HD + row2) * NSEQ + sc;
  const short* vg3 = vtws + ((long)bh * HD + row3) * NSEQ + sc;
  int lds0 = (wk * 32) * 64 + lane * 8;

  // prologue: tile 0 -> buf 0
  GLL(kg0, KB + lds0);
  GLL(kg1, KB + lds0 + 512);
  GLL(kg2, KB + lds0 + 1024);
  GLL(kg3, KB + lds0 + 1536);
  GLL(vg0, VB + lds0);
  GLL(vg1, VB + lds0 + 512);
  GLL(vg2, VB + lds0 + 1024);
  GLL(vg3, VB + lds0 + 1536);

  for (int it = 0; it < 32; it++) {
    int cur = (it & 1) * 4096;
    __syncthreads();
    const short* Kc = KB + cur;
    const short* Vc = VB + cur;
    s8v ak[4];
#pragma unroll
    for (int ds = 0; ds < 4; ds++)
      ak[ds] = *(const s8v*)&Kc[(wk * 32 + l31) * 64 + (((2 * ds + hf) ^ (l31 & 7)) * 8)];
    s8v av[2][2];
#pragma unroll
    for (int nt = 0; nt < 2; nt++)
#pragma unroll
      for (int ks = 0; ks < 2; ks++)
        av[nt][ks] = *(const s8v*)&Vc[(nt * 32 + l31) * 64 + (((wk * 4 + ks * 2 + hf) ^ (l31 & 7)) * 8)];
    if (it < 31) {
      int nb = 4096 - cur;
      long koff = (long)(it + 1) * 64 * HD;
      int voff = (it + 1) * 64;
      GLL(kg0 + koff, KB + nb + lds0);
      GLL(kg1 + koff, KB + nb + lds0 + 512);
      GLL(kg2 + koff, KB + nb + lds0 + 1024);
      GLL(kg3 + koff, KB + nb + lds0 + 1536);
      GLL(vg0 + voff, VB + nb + lds0);
      GLL(vg1 + voff, VB + nb + lds0 + 512);
      GLL(vg2 + voff, VB + nb + lds0 + 1024);
      GLL(vg3 + voff, VB + nb + lds0 + 1536);
    }
    // per q-row-tile: S^T -> exp2 -> pack -> exchange -> PV (all registers)
#pragma unroll
    for (int rt = 0; rt < 2; rt++) {
      f16v s = fz16;
#pragma unroll
      for (int ds = 0; ds < 4; ds++)
        s = __builtin_amdgcn_mfma_f32_32x32x16_bf16(ak[ds], qf[rt][ds], s, 0, 0, 0);
      f16v pv;
#pragma unroll
      for (int i = 0; i < 16; i++) pv[i] = __builtin_amdgcn_exp2f(s[i]);
      float ls = 0.f;
#pragma unroll
      for (int i = 0; i < 16; i++) ls += pv[i];
      ls += __shfl_xor(ls, 32);
      if (rt == 0) l_r0 += ls; else l_r1 += ls;
      // pack: d{2g},d{2g+1} hold keys 8g+4hf+{0..3} for qrow l31
      unsigned d0 = pk(pv[0],  pv[1]),  d1 = pk(pv[2],  pv[3]);
      unsigned d2 = pk(pv[4],  pv[5]),  d3 = pk(pv[6],  pv[7]);
      unsigned d4 = pk(pv[8],  pv[9]),  d5 = pk(pv[10], pv[11]);
      unsigned d6 = pk(pv[12], pv[13]), d7 = pk(pv[14], pv[15]);
      // ks = 0 (quads g=0,1)
      {
        unsigned send0 = hf ? d0 : d2, send1 = hf ? d1 : d3;
        unsigned own0  = hf ? d2 : d0, own1  = hf ? d3 : d1;
        unsigned recv0 = (unsigned)__shfl_xor((int)send0, 32);
        unsigned recv1 = (unsigned)__shfl_xor((int)send1, 32);
        u4v t;
        t.x = hf ? recv0 : own0;
        t.y = hf ? recv1 : own1;
        t.z = hf ? own0 : recv0;
        t.w = hf ? own1 : recv1;
        s8v bv = __builtin_bit_cast(s8v, t);
#pragma unroll
        for (int nt = 0; nt < 2; nt++)
          oacc[rt][nt] = __builtin_amdgcn_mfma_f32_32x32x16_bf16(av[nt][0], bv, oacc[rt][nt], 0, 0, 0);
      }
      // ks = 1 (quads g=2,3)
      {
        unsigned send0 = hf ? d4 : d6, send1 = hf ? d5 : d7;
        unsigned own0  = hf ? d6 : d4, own1  = hf ? d7 : d5;
        unsigned recv0 = (unsigned)__shfl_xor((int)send0, 32);
        unsigned recv1 = (unsigned)__shfl_xor((int)send1, 32);
        u4v t;
        t.x = hf ? recv0 : own0;
        t.y = hf ? recv1 : own1;
        t.z = hf ? own0 : recv0;
        t.w = hf ? own1 : recv1;
        s8v bv = __builtin_bit_cast(s8v, t);
#pragma unroll
        for (int nt = 0; nt < 2; nt++)
          oacc[rt][nt] = __builtin_amdgcn_mfma_f32_32x32x16_bf16(av[nt][1], bv, oacc[rt][nt], 0, 0, 0);
      }
    }
  }

  // ---- combine key halves (ALL oacc indices compile-time constants) ----
  __syncthreads();
  float* od = (float*)smem;            // region rt at rt*2176 floats: [32 qrow][68 pitch]
  float* ld = (float*)(smem + 17408);  // [2][32]

#define DUMP_HALF(RT, O0, O1, LR) do {                                        \
    _Pragma("unroll")                                                         \
    for (int g = 0; g < 4; g++) {                                             \
      f4v t0 = {(O0)[4*g], (O0)[4*g+1], (O0)[4*g+2], (O0)[4*g+3]};            \
      *(f4v*)&od[(RT) * 2176 + l31 * 68 + 8 * g + 4 * hf] = t0;               \
      f4v t1 = {(O1)[4*g], (O1)[4*g+1], (O1)[4*g+2], (O1)[4*g+3]};            \
      *(f4v*)&od[(RT) * 2176 + l31 * 68 + 32 + 8 * g + 4 * hf] = t1;          \
    }                                                                         \
    ld[(RT) * 32 + l31] = (LR);                                               \
  } while (0)

  if (wk == 0) DUMP_HALF(1, oacc[1][0], oacc[1][1], l_r1);
  else         DUMP_HALF(0, oacc[0][0], oacc[0][1], l_r0);

  __syncthreads();

#define STORE_HALF(RT, O0, O1, LR) do {                                       \
    float lt = (LR) + ld[(RT) * 32 + l31];                                    \
    float li = __builtin_amdgcn_rcpf(lt);                                     \
    long outbase = ((long)b * NSEQ + qbase + (RT) * 32 + l31) * CDIM + head * HD; \
    _Pragma("unroll")                                                         \
    for (int g = 0; g < 4; g++) {                                             \
      f4v p0 = *(const f4v*)&od[(RT) * 2176 + l31 * 68 + 8 * g + 4 * hf];     \
      short4 s0;                                                              \
      s0.x = f2bf_fast(((O0)[4*g]   + p0[0]) * li);                           \
      s0.y = f2bf_fast(((O0)[4*g+1] + p0[1]) * li);                           \
      s0.z = f2bf_fast(((O0)[4*g+2] + p0[2]) * li);                           \
      s0.w = f2bf_fast(((O0)[4*g+3] + p0[3]) * li);                           \
      *(short4*)&attn_out[outbase + 8 * g + 4 * hf] = s0;                     \
      f4v p1 = *(const f4v*)&od[(RT) * 2176 + l31 * 68 + 32 + 8 * g + 4 * hf];\
      short4 s1;                                                              \
      s1.x = f2bf_fast(((O1)[4*g]   + p1[0]) * li);                           \
      s1.y = f2bf_fast(((O1)[4*g+1] + p1[1]) * li);                           \
      s1.z = f2bf_fast(((O1)[4*g+2] + p1[2]) * li);                           \
      s1.w = f2bf_fast(((O1)[4*g+3] + p1[3]) * li);                           \
      *(short4*)&attn_out[outbase + 32 + 8 * g + 4 * hf] = s1;                \
    }                                                                         \
  } while (0)

  if (wk == 0) STORE_HALF(0, oacc[0][0], oacc[0][1], l_r0);
  else         STORE_HALF(1, oacc[1][0], oacc[1][1], l_r1);
}

extern "C" void kernel_launch(void* const* d_in, const int* in_sizes, int n_in,
                              void* d_out, int out_size, void* d_ws, size_t ws_size,
                              hipStream_t stream) {
  const float* x     = (const float*)d_in[0];
  const float* mask  = (const float*)d_in[1];
  const float* qkvw  = (const float*)d_in[2];
  const float* qkvb  = (const float*)d_in[3];
  const float* projw = (const float*)d_in[4];
  const float* projb = (const float*)d_in[5];
  const float* g1w   = (const float*)d_in[6];
  const float* g1b   = (const float*)d_in[7];
  const float* g2w   = (const float*)d_in[8];
  const float* g2b   = (const float*)d_in[9];
  float* out = (float*)d_out;

  char* ws = (char*)d_ws;
  short* x_bf    = (short*)(ws);               // 8 MiB
  short* w_qkv   = (short*)(ws + 8388608);     // 6 MiB
  short* w_proj  = (short*)(ws + 14680064);    // 2 MiB
  short* q_ws    = (short*)(ws + 16777216);    // 8 MiB (pre-scaled by 1/8)
  short* k_ws    = (short*)(ws + 25165824);    // 8 MiB (pre-scaled by gate*log2e)
  short* vt_ws   = (short*)(ws + 33554432);    // 8 MiB (transposed: b,h,d,n)
  short* attn_bf = (short*)(ws + 41943040);    // 8 MiB
  float* gate    = (float*)(ws + 50331648);    // 16 KiB

  cvt_gate_kernel<<<8208, 256, 0, stream>>>(x, qkvw, projw, mask, g1w, g1b, g2w, g2b,
                                            x_bf, w_qkv, w_proj, gate);

  dim3 gq(24, 32);
  gemm_qkv<<<gq, 256, 0, stream>>>(x_bf, w_qkv, qkvb, gate, q_ws, k_ws, vt_ws);

  attn_kernel<<<1024, 128, 0, stream>>>(q_ws, k_ws, vt_ws, attn_bf);

  dim3 gp(8, 64);
  gemm_proj<<<gp, 256, 0, stream>>>(attn_bf, w_proj, projb, out);
}